// Round 1
// baseline (1015.316 us; speedup 1.0000x reference)
//
#include <hip/hip_runtime.h>
#include <math.h>

#define VOCAB 20000
#define E     300
#define H     1024
#define G     8
#define NOUT  300
#define NANS  4000
#define B     64
#define NQ    32
#define NK    256

// ---------------------------------------------------------------------------
// K1: out[r, :] = emb[idx[r]] @ W + bias      (R rows, 32 rows/block, all 1024 cols)
// ---------------------------------------------------------------------------
__global__ __launch_bounds__(256) void proj_kernel(
    const int* __restrict__ idx, const float* __restrict__ emb,
    const float* __restrict__ W, const float* __restrict__ bias,
    float* __restrict__ out)
{
    __shared__ __align__(16) float a[32][E + 4];   // 32 x 304
    const int row0 = blockIdx.x * 32;
    const int t = threadIdx.x;

    // stage 32 emb rows (each 75 float4)
    for (int i = t; i < 32 * 75; i += 256) {
        int r = i / 75, e4 = i % 75;
        float4 v = reinterpret_cast<const float4*>(emb)[idx[row0 + r] * 75 + e4];
        *reinterpret_cast<float4*>(&a[r][e4 * 4]) = v;
    }
    __syncthreads();

    const int col = t * 4;          // 256 threads x 4 cols = 1024
    float acc[32][4] = {};

    for (int e4 = 0; e4 < 75; ++e4) {
        float4 w4[4];
        #pragma unroll
        for (int ee = 0; ee < 4; ++ee)
            w4[ee] = *reinterpret_cast<const float4*>(&W[(e4 * 4 + ee) * H + col]);
        #pragma unroll
        for (int r = 0; r < 32; ++r) {
            float4 a4 = *reinterpret_cast<const float4*>(&a[r][e4 * 4]);
            acc[r][0] += a4.x * w4[0].x; acc[r][1] += a4.x * w4[0].y;
            acc[r][2] += a4.x * w4[0].z; acc[r][3] += a4.x * w4[0].w;
            acc[r][0] += a4.y * w4[1].x; acc[r][1] += a4.y * w4[1].y;
            acc[r][2] += a4.y * w4[1].z; acc[r][3] += a4.y * w4[1].w;
            acc[r][0] += a4.z * w4[2].x; acc[r][1] += a4.z * w4[2].y;
            acc[r][2] += a4.z * w4[2].z; acc[r][3] += a4.z * w4[2].w;
            acc[r][0] += a4.w * w4[3].x; acc[r][1] += a4.w * w4[3].y;
            acc[r][2] += a4.w * w4[3].z; acc[r][3] += a4.w * w4[3].w;
        }
    }

    float4 bv = *reinterpret_cast<const float4*>(&bias[col]);
    #pragma unroll
    for (int r = 0; r < 32; ++r) {
        float4 o;
        o.x = acc[r][0] + bv.x; o.y = acc[r][1] + bv.y;
        o.z = acc[r][2] + bv.z; o.w = acc[r][3] + bv.w;
        *reinterpret_cast<float4*>(&out[(row0 + r) * H + col]) = o;
    }
}

// ---------------------------------------------------------------------------
// K2: logits[b,g,q,k] = sum_d hq[b,q,d]*Watt[d,g]*hk[b,k,d] + batt[g]
//     one block per (b,g); 256 threads; tile d by 32; 8q x 4k per thread
// ---------------------------------------------------------------------------
#define DT 32
__global__ __launch_bounds__(256) void logits_kernel(
    const float* __restrict__ hq, const float* __restrict__ hk,
    const float* __restrict__ Watt, const float* __restrict__ batt,
    float* __restrict__ logits)
{
    const int b = blockIdx.x, g = blockIdx.y;
    __shared__ __align__(16) float Aq[NQ][DT + 4];   // 32 x 36
    __shared__ __align__(16) float Hk[NK][DT + 4];   // 256 x 36
    const int t = threadIdx.x;
    const int lane = t & 63;
    const int q0 = (t >> 6) * 8;
    float acc[8][4] = {};

    for (int d0 = 0; d0 < H; d0 += DT) {
        for (int i = t; i < 32 * 8; i += 256) {
            int q = i >> 3, e4 = i & 7;
            int dd = d0 + e4 * 4;
            float4 v = *reinterpret_cast<const float4*>(&hq[(b * NQ + q) * H + dd]);
            v.x *= Watt[(dd + 0) * G + g];
            v.y *= Watt[(dd + 1) * G + g];
            v.z *= Watt[(dd + 2) * G + g];
            v.w *= Watt[(dd + 3) * G + g];
            *reinterpret_cast<float4*>(&Aq[q][e4 * 4]) = v;
        }
        for (int i = t; i < 256 * 8; i += 256) {
            int k = i >> 3, e4 = i & 7;
            *reinterpret_cast<float4*>(&Hk[k][e4 * 4]) =
                *reinterpret_cast<const float4*>(&hk[(b * NK + k) * H + d0 + e4 * 4]);
        }
        __syncthreads();
        #pragma unroll
        for (int d4 = 0; d4 < 8; ++d4) {
            float4 h4[4];
            #pragma unroll
            for (int c = 0; c < 4; ++c)
                h4[c] = *reinterpret_cast<const float4*>(&Hk[lane + 64 * c][d4 * 4]);
            #pragma unroll
            for (int j = 0; j < 8; ++j) {
                float4 a4 = *reinterpret_cast<const float4*>(&Aq[q0 + j][d4 * 4]);
                #pragma unroll
                for (int c = 0; c < 4; ++c)
                    acc[j][c] += a4.x * h4[c].x + a4.y * h4[c].y +
                                 a4.z * h4[c].z + a4.w * h4[c].w;
            }
        }
        __syncthreads();
    }

    const float bg = batt[g];
    #pragma unroll
    for (int j = 0; j < 8; ++j)
        #pragma unroll
        for (int c = 0; c < 4; ++c)
            logits[((b * G + g) * NQ + q0 + j) * NK + lane + 64 * c] = acc[j][c] + bg;
}

// ---------------------------------------------------------------------------
// K3: softmax over 8192 entries per (b,g), in place
// ---------------------------------------------------------------------------
__global__ __launch_bounds__(256) void softmax_kernel(float* __restrict__ att)
{
    float* p = att + blockIdx.x * (NQ * NK);
    const int t = threadIdx.x;
    __shared__ float red[4];

    float4 v[8];
    float lm = -1e30f;
    #pragma unroll
    for (int i = 0; i < 8; ++i) {
        v[i] = reinterpret_cast<float4*>(p)[t + i * 256];
        lm = fmaxf(lm, fmaxf(fmaxf(v[i].x, v[i].y), fmaxf(v[i].z, v[i].w)));
    }
    #pragma unroll
    for (int off = 32; off; off >>= 1) lm = fmaxf(lm, __shfl_xor(lm, off));
    if ((t & 63) == 0) red[t >> 6] = lm;
    __syncthreads();
    const float gm = fmaxf(fmaxf(red[0], red[1]), fmaxf(red[2], red[3]));

    float ls = 0.f;
    #pragma unroll
    for (int i = 0; i < 8; ++i) {
        v[i].x = __expf(v[i].x - gm);
        v[i].y = __expf(v[i].y - gm);
        v[i].z = __expf(v[i].z - gm);
        v[i].w = __expf(v[i].w - gm);
        ls += v[i].x + v[i].y + v[i].z + v[i].w;
    }
    #pragma unroll
    for (int off = 32; off; off >>= 1) ls += __shfl_xor(ls, off);
    __syncthreads();
    if ((t & 63) == 0) red[t >> 6] = ls;
    __syncthreads();
    const float inv = 1.f / (red[0] + red[1] + red[2] + red[3]);
    #pragma unroll
    for (int i = 0; i < 8; ++i) {
        float4 o;
        o.x = v[i].x * inv; o.y = v[i].y * inv;
        o.z = v[i].z * inv; o.w = v[i].w * inv;
        reinterpret_cast<float4*>(p)[t + i * 256] = o;
    }
}

// ---------------------------------------------------------------------------
// K4: pooled[b,g,d] = sum_q hq[b,q,d] * (sum_k att[b,g,q,k]*hk[b,k,d])
//     block per (b,g,d-half); 512 threads, 1 d each; att tile in LDS
// ---------------------------------------------------------------------------
__global__ __launch_bounds__(512) void pooled_kernel(
    const float* __restrict__ att, const float* __restrict__ hk,
    const float* __restrict__ hq, float* __restrict__ pooled)
{
    const int b = blockIdx.x, g = blockIdx.y, dh = blockIdx.z;
    __shared__ __align__(16) float A[NQ][NK];   // 32KB
    const int t = threadIdx.x;
    for (int i = t; i < 32 * 64; i += 512) {
        int q = i >> 6, k4 = i & 63;
        *reinterpret_cast<float4*>(&A[q][k4 * 4]) =
            *reinterpret_cast<const float4*>(&att[((b * G + g) * NQ + q) * NK + k4 * 4]);
    }
    __syncthreads();

    const int d = dh * 512 + t;
    const float* hkb = hk + (b * NK) * H + d;
    float acc[NQ] = {};
    for (int k4 = 0; k4 < 64; ++k4) {
        float h0 = hkb[(k4 * 4 + 0) * H];
        float h1 = hkb[(k4 * 4 + 1) * H];
        float h2 = hkb[(k4 * 4 + 2) * H];
        float h3 = hkb[(k4 * 4 + 3) * H];
        #pragma unroll
        for (int q = 0; q < NQ; ++q) {
            float4 a4 = *reinterpret_cast<const float4*>(&A[q][k4 * 4]);
            acc[q] += a4.x * h0 + a4.y * h1 + a4.z * h2 + a4.w * h3;
        }
    }
    float r = 0.f;
    #pragma unroll
    for (int q = 0; q < NQ; ++q)
        r += hq[(b * NQ + q) * H + d] * acc[q];
    pooled[(b * G + g) * H + d] = r;
}

// ---------------------------------------------------------------------------
// K5: partial[ks,b,n] = sum_{k in ks-range} pooled[b,k]*Wout[k,n]
//     grid (64 ksplits x 4 btiles); 128 k per split, 16 b per tile
// ---------------------------------------------------------------------------
__global__ __launch_bounds__(256) void outproj_kernel(
    const float* __restrict__ pooled, const float* __restrict__ Wout,
    float* __restrict__ partial)
{
    const int ks = blockIdx.x;
    const int bt = blockIdx.y;
    __shared__ __align__(16) float P[16][132];
    const int t = threadIdx.x;
    const int k0 = ks * 128;
    for (int i = t; i < 16 * 32; i += 256) {
        int bi = i >> 5, k4 = i & 31;
        *reinterpret_cast<float4*>(&P[bi][k4 * 4]) =
            *reinterpret_cast<const float4*>(&pooled[(bt * 16 + bi) * (G * H) + k0 + k4 * 4]);
    }
    __syncthreads();
    for (int n = t; n < NOUT; n += 256) {
        float acc[16] = {};
        for (int k = 0; k < 128; ++k) {
            float w = Wout[(k0 + k) * NOUT + n];
            #pragma unroll
            for (int bi = 0; bi < 16; ++bi) acc[bi] += P[bi][k] * w;
        }
        #pragma unroll
        for (int bi = 0; bi < 16; ++bi)
            partial[(ks * B + bt * 16 + bi) * 304 + n] = acc[bi];
    }
}

// ---------------------------------------------------------------------------
// K6: outv[b,n] = bout[n] + sum_ks partial[ks,b,n]
// ---------------------------------------------------------------------------
__global__ __launch_bounds__(256) void reduce_out_kernel(
    const float* __restrict__ partial, const float* __restrict__ bout,
    float* __restrict__ outv)
{
    const int i = blockIdx.x * 256 + threadIdx.x;   // 75*256 = 19200 = 64*300
    const int b = i / NOUT, n = i % NOUT;
    float acc = bout[n];
    for (int ks = 0; ks < 64; ++ks)
        acc += partial[(ks * B + b) * 304 + n];
    outv[b * 304 + n] = acc;
}

// ---------------------------------------------------------------------------
// K7: sim[b,a] = outv[b]·glove[a]; d_out = log_softmax over a
// ---------------------------------------------------------------------------
__global__ __launch_bounds__(256) void sim_lsm_kernel(
    const float* __restrict__ outv, const float* __restrict__ glove,
    float* __restrict__ dout)
{
    const int b = blockIdx.x;
    const int t = threadIdx.x;
    __shared__ __align__(16) float ov[304];
    __shared__ float sim[NANS];
    __shared__ float red[4];

    for (int i = t; i < 76; i += 256)
        reinterpret_cast<float4*>(ov)[i] = reinterpret_cast<const float4*>(outv + b * 304)[i];
    __syncthreads();

    float lmax = -1e30f;
    for (int a = t; a < NANS; a += 256) {
        float acc = 0.f;
        #pragma unroll 5
        for (int n4 = 0; n4 < 75; ++n4) {
            float4 gv = *reinterpret_cast<const float4*>(&glove[a * NOUT + n4 * 4]);
            float4 o4 = *reinterpret_cast<const float4*>(&ov[n4 * 4]);
            acc += gv.x * o4.x + gv.y * o4.y + gv.z * o4.z + gv.w * o4.w;
        }
        sim[a] = acc;
        lmax = fmaxf(lmax, acc);
    }
    #pragma unroll
    for (int off = 32; off; off >>= 1) lmax = fmaxf(lmax, __shfl_xor(lmax, off));
    if ((t & 63) == 0) red[t >> 6] = lmax;
    __syncthreads();
    const float gm = fmaxf(fmaxf(red[0], red[1]), fmaxf(red[2], red[3]));

    float ls = 0.f;
    for (int a = t; a < NANS; a += 256) ls += __expf(sim[a] - gm);
    #pragma unroll
    for (int off = 32; off; off >>= 1) ls += __shfl_xor(ls, off);
    __syncthreads();
    if ((t & 63) == 0) red[t >> 6] = ls;
    __syncthreads();
    const float lg = logf(red[0] + red[1] + red[2] + red[3]);

    for (int a = t; a < NANS; a += 256)
        dout[b * NANS + a] = sim[a] - gm - lg;
}

// ---------------------------------------------------------------------------
extern "C" void kernel_launch(void* const* d_in, const int* in_sizes, int n_in,
                              void* d_out, int out_size, void* d_ws, size_t ws_size,
                              hipStream_t stream)
{
    (void)in_sizes; (void)n_in; (void)out_size; (void)ws_size;
    const int*   he_q  = (const int*)  d_in[0];
    const int*   he_k  = (const int*)  d_in[1];
    const float* emb   = (const float*)d_in[2];
    const float* Wq    = (const float*)d_in[3];
    const float* bq    = (const float*)d_in[4];
    const float* Wk    = (const float*)d_in[5];
    const float* bk    = (const float*)d_in[6];
    const float* Watt  = (const float*)d_in[7];
    const float* batt  = (const float*)d_in[8];
    const float* Wout  = (const float*)d_in[9];
    const float* bout  = (const float*)d_in[10];
    const float* glove = (const float*)d_in[11];
    float* out = (float*)d_out;

    float* ws      = (float*)d_ws;
    float* hq      = ws;                    // 2,097,152
    float* hk      = hq + 2097152;          // 16,777,216
    float* att     = hk + 16777216;         // 4,194,304 (logits, softmaxed in place)
    float* pooled  = att + 4194304;         // 524,288
    float* partial = pooled + 524288;       // 64*64*304 = 1,245,184
    float* outv    = partial + 1245184;     // 64*304 = 19,456

    proj_kernel<<<dim3((B * NQ) / 32), 256, 0, stream>>>(he_q, emb, Wq, bq, hq);
    proj_kernel<<<dim3((B * NK) / 32), 256, 0, stream>>>(he_k, emb, Wk, bk, hk);
    logits_kernel<<<dim3(B, G), 256, 0, stream>>>(hq, hk, Watt, batt, att);
    softmax_kernel<<<dim3(B * G), 256, 0, stream>>>(att);
    pooled_kernel<<<dim3(B, G, 2), 512, 0, stream>>>(att, hk, hq, pooled);
    outproj_kernel<<<dim3(64, 4), 256, 0, stream>>>(pooled, Wout, partial);
    reduce_out_kernel<<<dim3(75), 256, 0, stream>>>(partial, bout, outv);
    sim_lsm_kernel<<<dim3(B), 256, 0, stream>>>(outv, glove, out);
}

// Round 2
// 407.283 us; speedup vs baseline: 2.4929x; 2.4929x over previous
//
#include <hip/hip_runtime.h>
#include <math.h>

#define VOCAB 20000
#define E     300
#define EP    320          // padded K for proj GEMM (10 k-steps of 32)
#define H     1024
#define G     8
#define NOUT  300
#define NANS  4000
#define B     64
#define NQ    32
#define NK    256

typedef __attribute__((ext_vector_type(8))) short bf16x8;
typedef __attribute__((ext_vector_type(4))) float f32x4;

__device__ inline ushort f2bf(float x) {
    union { float f; unsigned u; } c; c.f = x;
    unsigned r = c.u + 0x7FFF + ((c.u >> 16) & 1);   // RNE
    return (ushort)(r >> 16);
}
__device__ inline float bf2f(ushort x) {
    union { unsigned u; float f; } c; c.u = ((unsigned)x) << 16;
    return c.f;
}
#define MFMA(a, b, c) __builtin_amdgcn_mfma_f32_16x16x32_bf16((a), (b), (c), 0, 0, 0)

// ---------------------------------------------------------------------------
// P0: WT[h][e] (bf16, e padded to 320) from W[e][h] f32.  grid (16, 2)
// ---------------------------------------------------------------------------
__global__ __launch_bounds__(256) void prep_wt(
    const float* __restrict__ Wq, const float* __restrict__ Wk,
    ushort* __restrict__ WTq, ushort* __restrict__ WTk)
{
    const float* W = blockIdx.y ? Wk : Wq;
    ushort* WT = blockIdx.y ? WTk : WTq;
    const int h0 = blockIdx.x * 64;
    __shared__ ushort lds[64][EP + 8];
    for (int i = threadIdx.x; i < 64 * EP; i += 256) {
        int e = i / 64, hh = i % 64;                 // coalesced along h
        float v = (e < E) ? W[e * H + h0 + hh] : 0.f;
        lds[hh][e] = f2bf(v);
    }
    __syncthreads();
    for (int i = threadIdx.x; i < 64 * EP; i += 256) {
        int hh = i / EP, e = i % EP;                 // coalesced along e
        WT[(h0 + hh) * EP + e] = lds[hh][e];
    }
}

// ---------------------------------------------------------------------------
// P1: MFMA gather-GEMM  out = emb[idx] @ W + bias   (M-tile 32, N-tile 256)
// MODE 0 (hq): also write hqw[b][g][q][d] = (out * Watt[d][g]) bf16
// MODE 1 (hk): also write hkT[b][d][k] bf16 via LDS transpose bounce
// ---------------------------------------------------------------------------
template <int MODE>
__global__ __launch_bounds__(256) void proj_mfma(
    const int* __restrict__ idx, const float* __restrict__ emb,
    const ushort* __restrict__ WT, const float* __restrict__ bias,
    const float* __restrict__ watt,
    ushort* __restrict__ out_bf16, ushort* __restrict__ out2)
{
    __shared__ ushort lds[32 * 328];                 // also reused [256][40] in MODE 1
    const int r0 = blockIdx.x * 32;
    const int n0 = blockIdx.y * 256;
    const int t = threadIdx.x;

    // stage 32 gathered emb rows as bf16, zero-padded to 320
    for (int i = t; i < 32 * 80; i += 256) {
        int r = i / 80, e4 = (i % 80) * 4;
        ushort4 o;
        if (e4 < E) {
            float4 v = *(const float4*)(emb + idx[r0 + r] * E + e4);
            o.x = f2bf(v.x); o.y = f2bf(v.y); o.z = f2bf(v.z); o.w = f2bf(v.w);
        } else o = ushort4{0, 0, 0, 0};
        *(ushort4*)(lds + r * 328 + e4) = o;
    }
    __syncthreads();

    const int w = t >> 6, l = t & 63, lr = l & 15, lc = l >> 4;
    const int nw = n0 + w * 64;
    f32x4 acc[2][4] = {};
    const ushort* wtp = WT + (nw + lr) * EP + lc * 8;
    const ushort* ap  = lds + lr * 328 + lc * 8;

    #pragma unroll 2
    for (int kk = 0; kk < 10; ++kk) {
        bf16x8 a0 = *(const bf16x8*)(ap + kk * 32);
        bf16x8 a1 = *(const bf16x8*)(ap + 16 * 328 + kk * 32);
        #pragma unroll
        for (int nt = 0; nt < 4; ++nt) {
            bf16x8 bfr = *(const bf16x8*)(wtp + nt * 16 * EP + kk * 32);
            acc[0][nt] = MFMA(a0, bfr, acc[0][nt]);
            acc[1][nt] = MFMA(a1, bfr, acc[1][nt]);
        }
    }

    if (MODE == 0) {
        const int b = blockIdx.x;                    // 32 rows == one b
        #pragma unroll
        for (int mt = 0; mt < 2; ++mt)
        #pragma unroll
        for (int nt = 0; nt < 4; ++nt) {
            const int col = nw + nt * 16 + lr;
            const int q = mt * 16 + lc * 4;
            const float bv = bias[col];
            float wv[8];
            *(float4*)(wv)     = *(const float4*)(watt + col * 8);
            *(float4*)(wv + 4) = *(const float4*)(watt + col * 8 + 4);
            #pragma unroll
            for (int r = 0; r < 4; ++r) {
                float v = acc[mt][nt][r] + bv;
                out_bf16[(b * 32 + q + r) * H + col] = f2bf(v);
                #pragma unroll
                for (int g = 0; g < 8; ++g)
                    out2[((b * 8 + g) * 32 + q + r) * H + col] = f2bf(v * wv[g]);
            }
        }
    } else {
        const int b = r0 >> 8, k0 = r0 & 255;
        __syncthreads();                             // done reading A tile
        #pragma unroll
        for (int mt = 0; mt < 2; ++mt)
        #pragma unroll
        for (int nt = 0; nt < 4; ++nt) {
            const int col = nw + nt * 16 + lr;
            const int kq = mt * 16 + lc * 4;
            const float bv = bias[col];
            #pragma unroll
            for (int r = 0; r < 4; ++r) {
                ushort v = f2bf(acc[mt][nt][r] + bv);
                out_bf16[(r0 + kq + r) * H + col] = v;
                lds[(w * 64 + nt * 16 + lr) * 40 + kq + r] = v;   // [256 d][40]
            }
        }
        __syncthreads();
        for (int i = t; i < 1024; i += 256) {        // 256 d-rows x 4 chunks(16B)
            int d = i >> 2, c = i & 3;
            *(bf16x8*)(out2 + b * (H * NK) + (n0 + d) * NK + k0 + c * 8) =
                *(const bf16x8*)(lds + d * 40 + c * 8);
        }
    }
}

// ---------------------------------------------------------------------------
// P2: logits[b,g,q,k] = hqw[b,g] @ hk[b]^T + batt[g]   block=(b,g), 4 waves
// ---------------------------------------------------------------------------
__global__ __launch_bounds__(256) void logits_mfma(
    const ushort* __restrict__ hqw, const ushort* __restrict__ hk,
    const float* __restrict__ batt, float* __restrict__ logits)
{
    const int b = blockIdx.x, g = blockIdx.y;
    const int t = threadIdx.x, w = t >> 6, l = t & 63, lr = l & 15, lc = l >> 4;
    const ushort* ap = hqw + ((b * 8 + g) * 32 + lr) * H + lc * 8;
    const ushort* bp = hk + (b * NK + w * 64 + lr) * H + lc * 8;
    f32x4 acc[2][4] = {};

    #pragma unroll 2
    for (int kk = 0; kk < 32; ++kk) {
        bf16x8 a0 = *(const bf16x8*)(ap + kk * 32);
        bf16x8 a1 = *(const bf16x8*)(ap + 16 * H + kk * 32);
        #pragma unroll
        for (int nt = 0; nt < 4; ++nt) {
            bf16x8 bfr = *(const bf16x8*)(bp + nt * 16 * H + kk * 32);
            acc[0][nt] = MFMA(a0, bfr, acc[0][nt]);
            acc[1][nt] = MFMA(a1, bfr, acc[1][nt]);
        }
    }

    const float bg = batt[g];
    float* lp = logits + (b * 8 + g) * (NQ * NK);
    #pragma unroll
    for (int mt = 0; mt < 2; ++mt)
    #pragma unroll
    for (int nt = 0; nt < 4; ++nt)
    #pragma unroll
    for (int r = 0; r < 4; ++r)
        lp[(mt * 16 + lc * 4 + r) * NK + w * 64 + nt * 16 + lr] = acc[mt][nt][r] + bg;
}

// ---------------------------------------------------------------------------
// P3: joint softmax over 8192 per (b,g); f32 in, bf16 out
// ---------------------------------------------------------------------------
__global__ __launch_bounds__(256) void softmax_kernel(
    const float* __restrict__ logits, ushort* __restrict__ att)
{
    const float* p = logits + blockIdx.x * (NQ * NK);
    ushort* o = att + blockIdx.x * (NQ * NK);
    const int t = threadIdx.x;
    __shared__ float red[4];

    float4 v[8];
    float lm = -1e30f;
    #pragma unroll
    for (int i = 0; i < 8; ++i) {
        v[i] = ((const float4*)p)[t + i * 256];
        lm = fmaxf(lm, fmaxf(fmaxf(v[i].x, v[i].y), fmaxf(v[i].z, v[i].w)));
    }
    #pragma unroll
    for (int off = 32; off; off >>= 1) lm = fmaxf(lm, __shfl_xor(lm, off));
    if ((t & 63) == 0) red[t >> 6] = lm;
    __syncthreads();
    const float gm = fmaxf(fmaxf(red[0], red[1]), fmaxf(red[2], red[3]));

    float ls = 0.f;
    #pragma unroll
    for (int i = 0; i < 8; ++i) {
        v[i].x = __expf(v[i].x - gm); v[i].y = __expf(v[i].y - gm);
        v[i].z = __expf(v[i].z - gm); v[i].w = __expf(v[i].w - gm);
        ls += v[i].x + v[i].y + v[i].z + v[i].w;
    }
    #pragma unroll
    for (int off = 32; off; off >>= 1) ls += __shfl_xor(ls, off);
    __syncthreads();
    if ((t & 63) == 0) red[t >> 6] = ls;
    __syncthreads();
    const float inv = 1.f / (red[0] + red[1] + red[2] + red[3]);
    #pragma unroll
    for (int i = 0; i < 8; ++i) {
        ushort4 u;
        u.x = f2bf(v[i].x * inv); u.y = f2bf(v[i].y * inv);
        u.z = f2bf(v[i].z * inv); u.w = f2bf(v[i].w * inv);
        ((ushort4*)o)[t + i * 256] = u;
    }
}

// ---------------------------------------------------------------------------
// P4: ctx = att[b,g] @ hk[b] (MFMA, via hkT), then pooled[b,g,d]=sum_q hq*ctx
//     block=(b,g), 4 waves x 256 d each
// ---------------------------------------------------------------------------
__global__ __launch_bounds__(256) void pooled_mfma(
    const ushort* __restrict__ att, const ushort* __restrict__ hkT,
    const ushort* __restrict__ hq, float* __restrict__ pooled)
{
    const int b = blockIdx.x, g = blockIdx.y;
    const int t = threadIdx.x, w = t >> 6, l = t & 63, lr = l & 15, lc = l >> 4;
    const ushort* ap = att + ((b * 8 + g) * 32 + lr) * NK + lc * 8;
    const ushort* bp = hkT + b * (H * NK) + (w * 256 + lr) * NK + lc * 8;
    f32x4 acc[2][16] = {};

    #pragma unroll 2
    for (int kk = 0; kk < 8; ++kk) {
        bf16x8 a0 = *(const bf16x8*)(ap + kk * 32);
        bf16x8 a1 = *(const bf16x8*)(ap + 16 * NK + kk * 32);
        #pragma unroll
        for (int nt = 0; nt < 16; ++nt) {
            bf16x8 bfr = *(const bf16x8*)(bp + nt * 16 * NK + kk * 32);
            acc[0][nt] = MFMA(a0, bfr, acc[0][nt]);
            acc[1][nt] = MFMA(a1, bfr, acc[1][nt]);
        }
    }

    const ushort* hqb = hq + b * NQ * H;
    #pragma unroll
    for (int nt = 0; nt < 16; ++nt) {
        const int d = w * 256 + nt * 16 + lr;
        float s = 0.f;
        #pragma unroll
        for (int mt = 0; mt < 2; ++mt) {
            const int q = mt * 16 + lc * 4;
            #pragma unroll
            for (int r = 0; r < 4; ++r)
                s += bf2f(hqb[(q + r) * H + d]) * acc[mt][nt][r];
        }
        s += __shfl_xor(s, 16);
        s += __shfl_xor(s, 32);
        if (l < 16) pooled[(b * 8 + g) * H + d] = s;
    }
}

// ---------------------------------------------------------------------------
// K5/K6/K7: unchanged fp32 tail
// ---------------------------------------------------------------------------
__global__ __launch_bounds__(256) void outproj_kernel(
    const float* __restrict__ pooled, const float* __restrict__ Wout,
    float* __restrict__ partial)
{
    const int ks = blockIdx.x;
    const int bt = blockIdx.y;
    __shared__ __align__(16) float P[16][132];
    const int t = threadIdx.x;
    const int k0 = ks * 128;
    for (int i = t; i < 16 * 32; i += 256) {
        int bi = i >> 5, k4 = i & 31;
        *(float4*)(&P[bi][k4 * 4]) =
            *(const float4*)(&pooled[(bt * 16 + bi) * (G * H) + k0 + k4 * 4]);
    }
    __syncthreads();
    for (int n = t; n < NOUT; n += 256) {
        float acc[16] = {};
        for (int k = 0; k < 128; ++k) {
            float wv = Wout[(k0 + k) * NOUT + n];
            #pragma unroll
            for (int bi = 0; bi < 16; ++bi) acc[bi] += P[bi][k] * wv;
        }
        #pragma unroll
        for (int bi = 0; bi < 16; ++bi)
            partial[(ks * B + bt * 16 + bi) * 304 + n] = acc[bi];
    }
}

__global__ __launch_bounds__(256) void reduce_out_kernel(
    const float* __restrict__ partial, const float* __restrict__ bout,
    float* __restrict__ outv)
{
    const int i = blockIdx.x * 256 + threadIdx.x;
    const int b = i / NOUT, n = i % NOUT;
    float acc = bout[n];
    for (int ks = 0; ks < 64; ++ks)
        acc += partial[(ks * B + b) * 304 + n];
    outv[b * 304 + n] = acc;
}

__global__ __launch_bounds__(256) void sim_lsm_kernel(
    const float* __restrict__ outv, const float* __restrict__ glove,
    float* __restrict__ dout)
{
    const int b = blockIdx.x;
    const int t = threadIdx.x;
    __shared__ __align__(16) float ov[304];
    __shared__ float sim[NANS];
    __shared__ float red[4];

    for (int i = t; i < 76; i += 256)
        ((float4*)ov)[i] = ((const float4*)(outv + b * 304))[i];
    __syncthreads();

    float lmax = -1e30f;
    for (int a = t; a < NANS; a += 256) {
        float acc = 0.f;
        #pragma unroll 5
        for (int n4 = 0; n4 < 75; ++n4) {
            float4 gv = *(const float4*)(&glove[a * NOUT + n4 * 4]);
            float4 o4 = *(const float4*)(&ov[n4 * 4]);
            acc += gv.x * o4.x + gv.y * o4.y + gv.z * o4.z + gv.w * o4.w;
        }
        sim[a] = acc;
        lmax = fmaxf(lmax, acc);
    }
    #pragma unroll
    for (int off = 32; off; off >>= 1) lmax = fmaxf(lmax, __shfl_xor(lmax, off));
    if ((t & 63) == 0) red[t >> 6] = lmax;
    __syncthreads();
    const float gm = fmaxf(fmaxf(red[0], red[1]), fmaxf(red[2], red[3]));

    float ls = 0.f;
    for (int a = t; a < NANS; a += 256) ls += __expf(sim[a] - gm);
    #pragma unroll
    for (int off = 32; off; off >>= 1) ls += __shfl_xor(ls, off);
    __syncthreads();
    if ((t & 63) == 0) red[t >> 6] = ls;
    __syncthreads();
    const float lg = logf(red[0] + red[1] + red[2] + red[3]);

    for (int a = t; a < NANS; a += 256)
        dout[b * NANS + a] = sim[a] - gm - lg;
}

// ---------------------------------------------------------------------------
extern "C" void kernel_launch(void* const* d_in, const int* in_sizes, int n_in,
                              void* d_out, int out_size, void* d_ws, size_t ws_size,
                              hipStream_t stream)
{
    (void)in_sizes; (void)n_in; (void)out_size; (void)ws_size;
    const int*   he_q  = (const int*)  d_in[0];
    const int*   he_k  = (const int*)  d_in[1];
    const float* emb   = (const float*)d_in[2];
    const float* Wq    = (const float*)d_in[3];
    const float* bq    = (const float*)d_in[4];
    const float* Wk    = (const float*)d_in[5];
    const float* bk    = (const float*)d_in[6];
    const float* Watt  = (const float*)d_in[7];
    const float* batt  = (const float*)d_in[8];
    const float* Wout  = (const float*)d_in[9];
    const float* bout  = (const float*)d_in[10];
    const float* glove = (const float*)d_in[11];
    float* out = (float*)d_out;

    ushort* WTq    = (ushort*)d_ws;                  //  327,680 sh
    ushort* WTk    = WTq + 327680;                   //  327,680 sh
    ushort* hq_bf  = WTk + 327680;                   //  2,097,152 sh  [b][q][d]
    ushort* hqw    = hq_bf + 2097152;                // 16,777,216 sh  [b][g][q][d]
    ushort* hk_bf  = hqw + 16777216;                 // 16,777,216 sh  [b][k][d]
    ushort* hkT    = hk_bf + 16777216;               // 16,777,216 sh  [b][d][k]
    float*  logit  = (float*)(hkT + 16777216);       //  4,194,304 f32
    ushort* att    = (ushort*)(logit + 4194304);     //  4,194,304 sh
    float*  pooled = (float*)(att + 4194304);        //    524,288 f32
    float*  partial= pooled + 524288;                //  1,245,184 f32
    float*  outv   = partial + 1245184;              //     19,456 f32

    prep_wt<<<dim3(16, 2), 256, 0, stream>>>(Wq, Wk, WTq, WTk);
    proj_mfma<0><<<dim3(64, 4), 256, 0, stream>>>(he_q, emb, WTq, bq, Watt, hq_bf, hqw);
    proj_mfma<1><<<dim3(512, 4), 256, 0, stream>>>(he_k, emb, WTk, bk, Watt, hk_bf, hkT);
    logits_mfma<<<dim3(64, 8), 256, 0, stream>>>(hqw, hk_bf, batt, logit);
    softmax_kernel<<<dim3(512), 256, 0, stream>>>(logit, att);
    pooled_mfma<<<dim3(64, 8), 256, 0, stream>>>(att, hkT, hq_bf, pooled);
    outproj_kernel<<<dim3(64, 4), 256, 0, stream>>>(pooled, Wout, partial);
    reduce_out_kernel<<<dim3(75), 256, 0, stream>>>(partial, bout, outv);
    sim_lsm_kernel<<<dim3(64), 256, 0, stream>>>(outv, glove, out);
}

// Round 3
// 310.174 us; speedup vs baseline: 3.2734x; 1.3131x over previous
//
#include <hip/hip_runtime.h>
#include <math.h>

#define VOCAB 20000
#define E     300
#define EP    320          // padded K for proj GEMM (10 k-steps of 32)
#define H     1024
#define G     8
#define NOUT  300
#define NANS  4000
#define B     64
#define NQ    32
#define NK    256

typedef __attribute__((ext_vector_type(8))) short bf16x8;
typedef __attribute__((ext_vector_type(4))) float f32x4;

__device__ inline ushort f2bf(float x) {
    union { float f; unsigned u; } c; c.f = x;
    unsigned r = c.u + 0x7FFF + ((c.u >> 16) & 1);   // RNE
    return (ushort)(r >> 16);
}
__device__ inline float bf2f(ushort x) {
    union { unsigned u; float f; } c; c.u = ((unsigned)x) << 16;
    return c.f;
}
#define MFMA(a, b, c) __builtin_amdgcn_mfma_f32_16x16x32_bf16((a), (b), (c), 0, 0, 0)

// ---------------------------------------------------------------------------
// P0: WT[h][e] (bf16, e padded to 320) from W[e][h] f32.  grid (16, 2)
// ---------------------------------------------------------------------------
__global__ __launch_bounds__(256) void prep_wt(
    const float* __restrict__ Wq, const float* __restrict__ Wk,
    ushort* __restrict__ WTq, ushort* __restrict__ WTk)
{
    const float* W = blockIdx.y ? Wk : Wq;
    ushort* WT = blockIdx.y ? WTk : WTq;
    const int h0 = blockIdx.x * 64;
    __shared__ ushort lds[64][EP + 8];
    for (int i = threadIdx.x; i < 64 * EP; i += 256) {
        int e = i / 64, hh = i % 64;                 // coalesced along h
        float v = (e < E) ? W[e * H + h0 + hh] : 0.f;
        lds[hh][e] = f2bf(v);
    }
    __syncthreads();
    for (int i = threadIdx.x; i < 64 * EP; i += 256) {
        int hh = i / EP, e = i % EP;                 // coalesced along e
        WT[(h0 + hh) * EP + e] = lds[hh][e];
    }
}

// ---------------------------------------------------------------------------
// P1: MFMA gather-GEMM  out = emb[idx] @ W + bias   (M-tile 32, N-tile 256)
// MODE 0 (hq): also write hqw[b][g][q][d] = (out * Watt[d][g]) bf16
// MODE 1 (hk): also write hkT[b][d][k] bf16 via LDS transpose bounce
// ---------------------------------------------------------------------------
template <int MODE>
__global__ __launch_bounds__(256) void proj_mfma(
    const int* __restrict__ idx, const float* __restrict__ emb,
    const ushort* __restrict__ WT, const float* __restrict__ bias,
    const float* __restrict__ watt,
    ushort* __restrict__ out_bf16, ushort* __restrict__ out2)
{
    __shared__ ushort lds[32 * 328];                 // also reused [256][40] in MODE 1
    const int r0 = blockIdx.x * 32;
    const int n0 = blockIdx.y * 256;
    const int t = threadIdx.x;

    // stage 32 gathered emb rows as bf16, zero-padded to 320
    for (int i = t; i < 32 * 80; i += 256) {
        int r = i / 80, e4 = (i % 80) * 4;
        ushort4 o;
        if (e4 < E) {
            float4 v = *(const float4*)(emb + idx[r0 + r] * E + e4);
            o.x = f2bf(v.x); o.y = f2bf(v.y); o.z = f2bf(v.z); o.w = f2bf(v.w);
        } else o = ushort4{0, 0, 0, 0};
        *(ushort4*)(lds + r * 328 + e4) = o;
    }
    __syncthreads();

    const int w = t >> 6, l = t & 63, lr = l & 15, lc = l >> 4;
    const int nw = n0 + w * 64;
    f32x4 acc[2][4] = {};
    const ushort* wtp = WT + (nw + lr) * EP + lc * 8;
    const ushort* ap  = lds + lr * 328 + lc * 8;

    #pragma unroll 2
    for (int kk = 0; kk < 10; ++kk) {
        bf16x8 a0 = *(const bf16x8*)(ap + kk * 32);
        bf16x8 a1 = *(const bf16x8*)(ap + 16 * 328 + kk * 32);
        #pragma unroll
        for (int nt = 0; nt < 4; ++nt) {
            bf16x8 bfr = *(const bf16x8*)(wtp + nt * 16 * EP + kk * 32);
            acc[0][nt] = MFMA(a0, bfr, acc[0][nt]);
            acc[1][nt] = MFMA(a1, bfr, acc[1][nt]);
        }
    }

    if (MODE == 0) {
        const int b = blockIdx.x;                    // 32 rows == one b
        #pragma unroll
        for (int mt = 0; mt < 2; ++mt)
        #pragma unroll
        for (int nt = 0; nt < 4; ++nt) {
            const int col = nw + nt * 16 + lr;
            const int q = mt * 16 + lc * 4;
            const float bv = bias[col];
            float wv[8];
            *(float4*)(wv)     = *(const float4*)(watt + col * 8);
            *(float4*)(wv + 4) = *(const float4*)(watt + col * 8 + 4);
            #pragma unroll
            for (int r = 0; r < 4; ++r) {
                float v = acc[mt][nt][r] + bv;
                out_bf16[(b * 32 + q + r) * H + col] = f2bf(v);
                #pragma unroll
                for (int g = 0; g < 8; ++g)
                    out2[((b * 8 + g) * 32 + q + r) * H + col] = f2bf(v * wv[g]);
            }
        }
    } else {
        const int b = r0 >> 8, k0 = r0 & 255;
        __syncthreads();                             // done reading A tile
        #pragma unroll
        for (int mt = 0; mt < 2; ++mt)
        #pragma unroll
        for (int nt = 0; nt < 4; ++nt) {
            const int col = nw + nt * 16 + lr;
            const int kq = mt * 16 + lc * 4;
            const float bv = bias[col];
            #pragma unroll
            for (int r = 0; r < 4; ++r) {
                ushort v = f2bf(acc[mt][nt][r] + bv);
                out_bf16[(r0 + kq + r) * H + col] = v;
                lds[(w * 64 + nt * 16 + lr) * 40 + kq + r] = v;   // [256 d][40]
            }
        }
        __syncthreads();
        for (int i = t; i < 1024; i += 256) {        // 256 d-rows x 4 chunks(16B)
            int d = i >> 2, c = i & 3;
            *(bf16x8*)(out2 + b * (H * NK) + (n0 + d) * NK + k0 + c * 8) =
                *(const bf16x8*)(lds + d * 40 + c * 8);
        }
    }
}

// ---------------------------------------------------------------------------
// P2: logits[b,g,q,k] = hqw[b,g] @ hk[b]^T + batt[g]   block=(b,g), 4 waves
// ---------------------------------------------------------------------------
__global__ __launch_bounds__(256) void logits_mfma(
    const ushort* __restrict__ hqw, const ushort* __restrict__ hk,
    const float* __restrict__ batt, float* __restrict__ logits)
{
    const int b = blockIdx.x, g = blockIdx.y;
    const int t = threadIdx.x, w = t >> 6, l = t & 63, lr = l & 15, lc = l >> 4;
    const ushort* ap = hqw + ((b * 8 + g) * 32 + lr) * H + lc * 8;
    const ushort* bp = hk + (b * NK + w * 64 + lr) * H + lc * 8;
    f32x4 acc[2][4] = {};

    #pragma unroll 2
    for (int kk = 0; kk < 32; ++kk) {
        bf16x8 a0 = *(const bf16x8*)(ap + kk * 32);
        bf16x8 a1 = *(const bf16x8*)(ap + 16 * H + kk * 32);
        #pragma unroll
        for (int nt = 0; nt < 4; ++nt) {
            bf16x8 bfr = *(const bf16x8*)(bp + nt * 16 * H + kk * 32);
            acc[0][nt] = MFMA(a0, bfr, acc[0][nt]);
            acc[1][nt] = MFMA(a1, bfr, acc[1][nt]);
        }
    }

    const float bg = batt[g];
    float* lp = logits + (b * 8 + g) * (NQ * NK);
    #pragma unroll
    for (int mt = 0; mt < 2; ++mt)
    #pragma unroll
    for (int nt = 0; nt < 4; ++nt)
    #pragma unroll
    for (int r = 0; r < 4; ++r)
        lp[(mt * 16 + lc * 4 + r) * NK + w * 64 + nt * 16 + lr] = acc[mt][nt][r] + bg;
}

// ---------------------------------------------------------------------------
// P3: joint softmax over 8192 per (b,g); f32 in, bf16 out
// ---------------------------------------------------------------------------
__global__ __launch_bounds__(256) void softmax_kernel(
    const float* __restrict__ logits, ushort* __restrict__ att)
{
    const float* p = logits + blockIdx.x * (NQ * NK);
    ushort* o = att + blockIdx.x * (NQ * NK);
    const int t = threadIdx.x;
    __shared__ float red[4];

    float4 v[8];
    float lm = -1e30f;
    #pragma unroll
    for (int i = 0; i < 8; ++i) {
        v[i] = ((const float4*)p)[t + i * 256];
        lm = fmaxf(lm, fmaxf(fmaxf(v[i].x, v[i].y), fmaxf(v[i].z, v[i].w)));
    }
    #pragma unroll
    for (int off = 32; off; off >>= 1) lm = fmaxf(lm, __shfl_xor(lm, off));
    if ((t & 63) == 0) red[t >> 6] = lm;
    __syncthreads();
    const float gm = fmaxf(fmaxf(red[0], red[1]), fmaxf(red[2], red[3]));

    float ls = 0.f;
    #pragma unroll
    for (int i = 0; i < 8; ++i) {
        v[i].x = __expf(v[i].x - gm); v[i].y = __expf(v[i].y - gm);
        v[i].z = __expf(v[i].z - gm); v[i].w = __expf(v[i].w - gm);
        ls += v[i].x + v[i].y + v[i].z + v[i].w;
    }
    #pragma unroll
    for (int off = 32; off; off >>= 1) ls += __shfl_xor(ls, off);
    __syncthreads();
    if ((t & 63) == 0) red[t >> 6] = ls;
    __syncthreads();
    const float inv = 1.f / (red[0] + red[1] + red[2] + red[3]);
    #pragma unroll
    for (int i = 0; i < 8; ++i) {
        ushort4 u;
        u.x = f2bf(v[i].x * inv); u.y = f2bf(v[i].y * inv);
        u.z = f2bf(v[i].z * inv); u.w = f2bf(v[i].w * inv);
        ((ushort4*)o)[t + i * 256] = u;
    }
}

// ---------------------------------------------------------------------------
// P4: ctx = att[b,g] @ hk[b] (MFMA, via hkT), then pooled[b,g,d]=sum_q hq*ctx
//     block=(b,g), 4 waves x 256 d each
// ---------------------------------------------------------------------------
__global__ __launch_bounds__(256) void pooled_mfma(
    const ushort* __restrict__ att, const ushort* __restrict__ hkT,
    const ushort* __restrict__ hq, float* __restrict__ pooled)
{
    const int b = blockIdx.x, g = blockIdx.y;
    const int t = threadIdx.x, w = t >> 6, l = t & 63, lr = l & 15, lc = l >> 4;
    const ushort* ap = att + ((b * 8 + g) * 32 + lr) * NK + lc * 8;
    const ushort* bp = hkT + b * (H * NK) + (w * 256 + lr) * NK + lc * 8;
    f32x4 acc[2][16] = {};

    #pragma unroll 2
    for (int kk = 0; kk < 8; ++kk) {
        bf16x8 a0 = *(const bf16x8*)(ap + kk * 32);
        bf16x8 a1 = *(const bf16x8*)(ap + 16 * NK + kk * 32);
        #pragma unroll
        for (int nt = 0; nt < 16; ++nt) {
            bf16x8 bfr = *(const bf16x8*)(bp + nt * 16 * NK + kk * 32);
            acc[0][nt] = MFMA(a0, bfr, acc[0][nt]);
            acc[1][nt] = MFMA(a1, bfr, acc[1][nt]);
        }
    }

    const ushort* hqb = hq + b * NQ * H;
    #pragma unroll
    for (int nt = 0; nt < 16; ++nt) {
        const int d = w * 256 + nt * 16 + lr;
        float s = 0.f;
        #pragma unroll
        for (int mt = 0; mt < 2; ++mt) {
            const int q = mt * 16 + lc * 4;
            #pragma unroll
            for (int r = 0; r < 4; ++r)
                s += bf2f(hqb[(q + r) * H + d]) * acc[mt][nt][r];
        }
        s += __shfl_xor(s, 16);
        s += __shfl_xor(s, 32);
        if (l < 16) pooled[(b * 8 + g) * H + d] = s;
    }
}

// ---------------------------------------------------------------------------
// K5/K6: fp32 out-projection with k-split + reduce
// ---------------------------------------------------------------------------
__global__ __launch_bounds__(256) void outproj_kernel(
    const float* __restrict__ pooled, const float* __restrict__ Wout,
    float* __restrict__ partial)
{
    const int ks = blockIdx.x;
    const int bt = blockIdx.y;
    __shared__ __align__(16) float P[16][132];
    const int t = threadIdx.x;
    const int k0 = ks * 128;
    for (int i = t; i < 16 * 32; i += 256) {
        int bi = i >> 5, k4 = i & 31;
        *(float4*)(&P[bi][k4 * 4]) =
            *(const float4*)(&pooled[(bt * 16 + bi) * (G * H) + k0 + k4 * 4]);
    }
    __syncthreads();
    for (int n = t; n < NOUT; n += 256) {
        float acc[16] = {};
        for (int k = 0; k < 128; ++k) {
            float wv = Wout[(k0 + k) * NOUT + n];
            #pragma unroll
            for (int bi = 0; bi < 16; ++bi) acc[bi] += P[bi][k] * wv;
        }
        #pragma unroll
        for (int bi = 0; bi < 16; ++bi)
            partial[(ks * B + bt * 16 + bi) * 304 + n] = acc[bi];
    }
}

__global__ __launch_bounds__(256) void reduce_out_kernel(
    const float* __restrict__ partial, const float* __restrict__ bout,
    float* __restrict__ outv)
{
    const int i = blockIdx.x * 256 + threadIdx.x;
    const int b = i / NOUT, n = i % NOUT;
    float acc = bout[n];
    for (int ks = 0; ks < 64; ++ks)
        acc += partial[(ks * B + b) * 304 + n];
    outv[b * 304 + n] = acc;
}

// ---------------------------------------------------------------------------
// S1: sim[b,a] = outv[b]·glove[a]  — 250 blocks x (16 answers x 64 b)
//     glove tile + full outv staged in LDS (rows padded to 308 floats)
// ---------------------------------------------------------------------------
__global__ __launch_bounds__(256) void sim_kernel(
    const float* __restrict__ outv, const float* __restrict__ glove,
    float* __restrict__ sim)
{
    __shared__ __align__(16) float ov[64][308];
    __shared__ __align__(16) float gl[16][308];
    const int t = threadIdx.x;
    const int a0 = blockIdx.x * 16;

    for (int i = t; i < 64 * 75; i += 256) {
        int r = i / 75, c = i % 75;
        *(float4*)(&ov[r][c * 4]) = *(const float4*)(&outv[r * 304 + c * 4]);
    }
    for (int i = t; i < 16 * 75; i += 256) {
        int r = i / 75, c = i % 75;
        *(float4*)(&gl[r][c * 4]) = *(const float4*)(&glove[(a0 + r) * NOUT + c * 4]);
    }
    __syncthreads();

    const int a = t & 15, bg = t >> 4;   // 16 answers x 16 b-groups(4 b each)
    float acc[4] = {};
    for (int k4 = 0; k4 < 75; ++k4) {
        float4 g = *(const float4*)(&gl[a][k4 * 4]);
        #pragma unroll
        for (int bi = 0; bi < 4; ++bi) {
            float4 o = *(const float4*)(&ov[bg * 4 + bi][k4 * 4]);
            acc[bi] += g.x * o.x + g.y * o.y + g.z * o.z + g.w * o.w;
        }
    }
    #pragma unroll
    for (int bi = 0; bi < 4; ++bi)
        sim[(bg * 4 + bi) * NANS + a0 + a] = acc[bi];
}

// ---------------------------------------------------------------------------
// S2: per-b log_softmax over 4000, write d_out
// ---------------------------------------------------------------------------
__global__ __launch_bounds__(256) void lsm_kernel(
    const float* __restrict__ sim, float* __restrict__ dout)
{
    const int b = blockIdx.x, t = threadIdx.x;
    const float* p = sim + b * NANS;
    __shared__ float red[4];

    float4 v[4];
    float lm = -1e30f;
    #pragma unroll
    for (int j = 0; j < 4; ++j) {
        int i = t + j * 256;
        if (i < 1000) {
            v[j] = ((const float4*)p)[i];
            lm = fmaxf(lm, fmaxf(fmaxf(v[j].x, v[j].y), fmaxf(v[j].z, v[j].w)));
        }
    }
    #pragma unroll
    for (int off = 32; off; off >>= 1) lm = fmaxf(lm, __shfl_xor(lm, off));
    if ((t & 63) == 0) red[t >> 6] = lm;
    __syncthreads();
    const float gm = fmaxf(fmaxf(red[0], red[1]), fmaxf(red[2], red[3]));

    float ls = 0.f;
    #pragma unroll
    for (int j = 0; j < 4; ++j) {
        int i = t + j * 256;
        if (i < 1000)
            ls += __expf(v[j].x - gm) + __expf(v[j].y - gm) +
                  __expf(v[j].z - gm) + __expf(v[j].w - gm);
    }
    #pragma unroll
    for (int off = 32; off; off >>= 1) ls += __shfl_xor(ls, off);
    __syncthreads();
    if ((t & 63) == 0) red[t >> 6] = ls;
    __syncthreads();
    const float sh = gm + logf(red[0] + red[1] + red[2] + red[3]);

    #pragma unroll
    for (int j = 0; j < 4; ++j) {
        int i = t + j * 256;
        if (i < 1000) {
            float4 o;
            o.x = v[j].x - sh; o.y = v[j].y - sh;
            o.z = v[j].z - sh; o.w = v[j].w - sh;
            ((float4*)(dout + b * NANS))[i] = o;
        }
    }
}

// ---------------------------------------------------------------------------
extern "C" void kernel_launch(void* const* d_in, const int* in_sizes, int n_in,
                              void* d_out, int out_size, void* d_ws, size_t ws_size,
                              hipStream_t stream)
{
    (void)in_sizes; (void)n_in; (void)out_size; (void)ws_size;
    const int*   he_q  = (const int*)  d_in[0];
    const int*   he_k  = (const int*)  d_in[1];
    const float* emb   = (const float*)d_in[2];
    const float* Wq    = (const float*)d_in[3];
    const float* bq    = (const float*)d_in[4];
    const float* Wk    = (const float*)d_in[5];
    const float* bk    = (const float*)d_in[6];
    const float* Watt  = (const float*)d_in[7];
    const float* batt  = (const float*)d_in[8];
    const float* Wout  = (const float*)d_in[9];
    const float* bout  = (const float*)d_in[10];
    const float* glove = (const float*)d_in[11];
    float* out = (float*)d_out;

    ushort* WTq    = (ushort*)d_ws;                  //  327,680 sh
    ushort* WTk    = WTq + 327680;                   //  327,680 sh
    ushort* hq_bf  = WTk + 327680;                   //  2,097,152 sh  [b][q][d]
    ushort* hqw    = hq_bf + 2097152;                // 16,777,216 sh  [b][g][q][d]
    ushort* hk_bf  = hqw + 16777216;                 // 16,777,216 sh  [b][k][d]
    ushort* hkT    = hk_bf + 16777216;               // 16,777,216 sh  [b][d][k]
    float*  logit  = (float*)(hkT + 16777216);       //  4,194,304 f32
    ushort* att    = (ushort*)(logit + 4194304);     //  4,194,304 sh
    float*  pooled = (float*)(att + 4194304);        //    524,288 f32
    float*  partial= pooled + 524288;                //  1,245,184 f32
    float*  outv   = partial + 1245184;              //     19,456 f32
    float*  sim    = outv + 19456;                   //    256,000 f32

    prep_wt<<<dim3(16, 2), 256, 0, stream>>>(Wq, Wk, WTq, WTk);
    proj_mfma<0><<<dim3(64, 4), 256, 0, stream>>>(he_q, emb, WTq, bq, Watt, hq_bf, hqw);
    proj_mfma<1><<<dim3(512, 4), 256, 0, stream>>>(he_k, emb, WTk, bk, Watt, hk_bf, hkT);
    logits_mfma<<<dim3(64, 8), 256, 0, stream>>>(hqw, hk_bf, batt, logit);
    softmax_kernel<<<dim3(512), 256, 0, stream>>>(logit, att);
    pooled_mfma<<<dim3(64, 8), 256, 0, stream>>>(att, hkT, hq_bf, pooled);
    outproj_kernel<<<dim3(64, 4), 256, 0, stream>>>(pooled, Wout, partial);
    reduce_out_kernel<<<dim3(75), 256, 0, stream>>>(partial, bout, outv);
    sim_kernel<<<dim3(250), 256, 0, stream>>>(outv, glove, sim);
    lsm_kernel<<<dim3(64), 256, 0, stream>>>(sim, out);
}